// Round 1
// baseline (882.862 us; speedup 1.0000x reference)
//
#include <hip/hip_runtime.h>

typedef float f32x4 __attribute__((ext_vector_type(4)));
typedef short bf16x8 __attribute__((ext_vector_type(8)));
typedef unsigned short ushort_t;

// ---------------- Threefry-2x32 (20 rounds), exact JAX semantics ----------------
__device__ __forceinline__ unsigned rotl32(unsigned x, unsigned r){ return (x << r) | (x >> (32u - r)); }

__device__ __forceinline__ void tf2x32(unsigned k0, unsigned k1, unsigned c0, unsigned c1,
                                       unsigned &o0, unsigned &o1){
  unsigned ks2 = k0 ^ k1 ^ 0x1BD11BDAu;
  unsigned x0 = c0 + k0, x1 = c1 + k1;
#define TFR(r) { x0 += x1; x1 = rotl32(x1, r); x1 ^= x0; }
  TFR(13) TFR(15) TFR(26) TFR(6)
  x0 += k1;  x1 += ks2 + 1u;
  TFR(17) TFR(29) TFR(16) TFR(24)
  x0 += ks2; x1 += k0 + 2u;
  TFR(13) TFR(15) TFR(26) TFR(6)
  x0 += k0;  x1 += k1 + 3u;
  TFR(17) TFR(29) TFR(16) TFR(24)
  x0 += k1;  x1 += ks2 + 4u;
  TFR(13) TFR(15) TFR(26) TFR(6)
  x0 += ks2; x1 += k0 + 5u;
#undef TFR
  o0 = x0; o1 = x1;
}

__device__ __forceinline__ float bits_to_u01(unsigned bits){
  return __uint_as_float((bits >> 9) | 0x3f800000u) - 1.0f;
}

// XLA ErfInv32 (Giles polynomial)
__device__ __forceinline__ float erfinv_f(float x){
  float w = -log1pf(-x * x);
  float p;
  if (w < 5.0f){
    w -= 2.5f;
    p = 2.81022636e-08f;
    p = 3.43273939e-07f + p * w;
    p = -3.5233877e-06f + p * w;
    p = -4.39150654e-06f + p * w;
    p = 0.00021858087f + p * w;
    p = -0.00125372503f + p * w;
    p = -0.00417768164f + p * w;
    p = 0.246640727f + p * w;
    p = 1.50140941f + p * w;
  } else {
    w = sqrtf(w) - 3.0f;
    p = -0.000200214257f;
    p = 0.000100950558f + p * w;
    p = 0.00134934322f + p * w;
    p = -0.00367342844f + p * w;
    p = 0.00573950773f + p * w;
    p = -0.0076224613f + p * w;
    p = 0.00943887047f + p * w;
    p = 1.00167406f + p * w;
    p = 2.83297682f + p * w;
  }
  return p * x;
}

__device__ __forceinline__ ushort_t f2bf(float f){
  unsigned u = __float_as_uint(f);
  unsigned r = u + 0x7fffu + ((u >> 16) & 1u);
  return (ushort_t)(r >> 16);
}
__device__ __forceinline__ float bf2f(ushort_t h){ return __uint_as_float(((unsigned)h) << 16); }

__device__ __forceinline__ float sigmf(float x){
  return __builtin_amdgcn_rcpf(1.0f + __expf(-x));
}
__device__ __forceinline__ float tanhf_(float x){
  float e = __expf(-2.0f * fabsf(x));
  float t = (1.0f - e) * __builtin_amdgcn_rcpf(1.0f + e);
  return copysignf(t, x);
}

// ---------------- geometry ----------------
// B=32768, OBS_LEN=8, IN_DIM=2, HID=128, 4H=512, PRED_LEN=12
constexpr int BT = 64;      // batch rows per block
constexpr int PITCH = 136;  // LDS row pitch in bf16 (conflict-free b128 reads)

// ---------------- prep: encoder weights -> bf16, bias sums ----------------
__global__ void prep_enc(const float* __restrict__ whh0, const float* __restrict__ wih1,
                         const float* __restrict__ whh1,
                         const float* __restrict__ bih0, const float* __restrict__ bhh0,
                         const float* __restrict__ bih1, const float* __restrict__ bhh1,
                         ushort_t* __restrict__ o0, ushort_t* __restrict__ o1, ushort_t* __restrict__ o2,
                         float* __restrict__ bias0, float* __restrict__ bias1){
  int tid = blockIdx.x * 256 + threadIdx.x;
  if (tid < 65536)        o0[tid] = f2bf(whh0[tid]);
  else if (tid < 131072)  o1[tid - 65536] = f2bf(wih1[tid - 65536]);
  else if (tid < 196608)  o2[tid - 131072] = f2bf(whh1[tid - 131072]);
  else if (tid < 197120){ int j = tid - 196608; bias0[j] = bih0[j] + bhh0[j]; }
  else if (tid < 197632){ int j = tid - 197120; bias1[j] = bih1[j] + bhh1[j]; }
}

// ---------------- prep: decoder sampled weights (key(2), partitionable threefry) ----------------
__global__ void prep_dec(
    const float* __restrict__ din_wmu, const float* __restrict__ din_wrho,
    const float* __restrict__ din_bmu, const float* __restrict__ din_brho,
    const float* __restrict__ dhid_wmu, const float* __restrict__ dhid_wrho,
    const float* __restrict__ dhid_bmu, const float* __restrict__ dhid_brho,
    const float* __restrict__ out_wmu, const float* __restrict__ out_wrho,
    const float* __restrict__ out_bmu, const float* __restrict__ out_brho,
    ushort_t* __restrict__ dwhid, float* __restrict__ dwin, float* __restrict__ dbin,
    float* __restrict__ dbhid, float* __restrict__ dwout, float* __restrict__ dbout){
  int tid = blockIdx.x * 256 + threadIdx.x;
  if (tid >= 12 * 68100) return;
  int s = tid / 68100, r = tid - s * 68100;
  unsigned sk0, sk1, gk0, gk1, b0, b1;
  // step_keys = split(key(2)=(0,2), 12): key_s = tf(key, 0, s)
  tf2x32(0u, 2u, 0u, (unsigned)s, sk0, sk1);
  int g, e; const float *mu, *rho;
  if (r < 1024)      { g = 0; e = r;          mu = din_wmu;  rho = din_wrho;  }
  else if (r < 1536) { g = 1; e = r - 1024;   mu = din_bmu;  rho = din_brho;  }
  else if (r < 67072){ g = 2; e = r - 1536;   mu = dhid_wmu; rho = dhid_wrho; }
  else if (r < 67584){ g = 3; e = r - 67072;  mu = dhid_bmu; rho = dhid_brho; }
  else if (r < 68096){ g = 4; e = r - 67584;  mu = out_wmu;  rho = out_wrho;  }
  else               { g = 5; e = r - 68096;  mu = out_bmu;  rho = out_brho;  }
  // k1..k6 = split(step_key, 6): key_g = tf(step_key, 0, g)
  tf2x32(sk0, sk1, 0u, (unsigned)g, gk0, gk1);
  // normal draw element e: bits = o0 ^ o1 of tf(key_g, 0, e)
  tf2x32(gk0, gk1, 0u, (unsigned)e, b0, b1);
  unsigned bits = b0 ^ b1;
  float u01 = bits_to_u01(bits);
  const float LO = __uint_as_float(0xBF7FFFFFu); // nextafter(-1,0)
  float u = u01 * 2.0f + LO;
  u = fmaxf(LO, u);
  float eps = 1.41421356237f * erfinv_f(u);
  float stdv = log1pf(expf(rho[e]));
  float val = mu[e] + stdv * eps;
  switch (g){
    case 0:  dwin [s * 1024 + e] = val; break;
    case 1:  dbin [s * 512  + e] = val; break;
    case 2:  dwhid[s * 65536 + e] = f2bf(val); break;
    case 3:  dbhid[s * 512  + e] = val; break;
    case 4:  dwout[s * 512  + e] = val; break;
    default: dbout[s * 4    + e] = val; break;
  }
}

// ---------------- prep: dropout mask bits (key(1)), bernoulli keep = u < 0.9f ----------------
__global__ void gen_mask(unsigned* __restrict__ maskw){
  unsigned w = blockIdx.x * 256 + threadIdx.x; // < 1048576 words
  unsigned word = 0;
  #pragma unroll 4
  for (int b = 0; b < 32; ++b){
    unsigned o0, o1;
    tf2x32(0u, 1u, 0u, w * 32u + (unsigned)b, o0, o1);
    unsigned bits = o0 ^ o1;
    float u = bits_to_u01(bits);
    word |= (u < 0.9f ? 1u : 0u) << b;
  }
  maskw[w] = word;
}

// ---------------- KL (deterministic; also an RNG-independent diagnostic) ----------------
__global__ void kl_kernel(
    const float* __restrict__ m0, const float* __restrict__ r0,
    const float* __restrict__ m1, const float* __restrict__ r1,
    const float* __restrict__ m2, const float* __restrict__ r2,
    const float* __restrict__ m3, const float* __restrict__ r3,
    const float* __restrict__ m4, const float* __restrict__ r4,
    const float* __restrict__ m5, const float* __restrict__ r5,
    float* __restrict__ out){
  __shared__ float red[1024];
  int tid = threadIdx.x;
  float s = 0.f;
  auto term = [](float mu, float rho){
    float stdv = log1pf(expf(rho));
    return logf(0.1f / stdv) + (stdv * stdv + mu * mu) * 50.0f - 0.5f;
  };
  for (int i = tid; i < 1024;  i += 1024) s += term(m0[i], r0[i]);
  for (int i = tid; i < 512;   i += 1024) s += term(m1[i], r1[i]);
  for (int i = tid; i < 65536; i += 1024) s += term(m2[i], r2[i]);
  for (int i = tid; i < 512;   i += 1024) s += term(m3[i], r3[i]);
  for (int i = tid; i < 512;   i += 1024) s += term(m4[i], r4[i]);
  if (tid < 4) s += term(m5[tid], r5[tid]);
  red[tid] = s;
  __syncthreads();
  for (int off = 512; off > 0; off >>= 1){
    if (tid < off) red[tid] += red[tid + off];
    __syncthreads();
  }
  if (tid == 0) out[1572864] = red[0];
}

// ---------------- fused LSTM GEMM helper: acc[gate][mt] += Hlds(64x128) @ W(512x128)^T ----------------
__device__ __forceinline__ void gemm_k128(const ushort_t* __restrict__ Hlds,
                                          const ushort_t* __restrict__ W,
                                          int wv, int lx, int lg, f32x4 acc[4][4]){
  #pragma unroll
  for (int ki = 0; ki < 4; ++ki){
    bf16x8 a[4];
    #pragma unroll
    for (int mt = 0; mt < 4; ++mt)
      a[mt] = *(const bf16x8*)(Hlds + (16 * mt + lx) * PITCH + 32 * ki + 8 * lg);
    #pragma unroll
    for (int g = 0; g < 4; ++g){
      bf16x8 b = *(const bf16x8*)(W + (128 * g + 16 * wv + lx) * 128 + 32 * ki + 8 * lg);
      #pragma unroll
      for (int mt = 0; mt < 4; ++mt)
        acc[g][mt] = __builtin_amdgcn_mfma_f32_16x16x32_bf16(a[mt], b, acc[g][mt], 0, 0, 0);
    }
  }
}

// ---------------- main fused kernel ----------------
__global__ __launch_bounds__(512, 2) void lstm_main(
    const float* __restrict__ obs,      // [32768][8][2]
    const float* __restrict__ wih0,     // [512][2] f32
    const ushort_t* __restrict__ whh0,  // [512][128] bf16
    const ushort_t* __restrict__ wih1,
    const ushort_t* __restrict__ whh1,
    const float* __restrict__ bias0,    // [512] (bih0+bhh0)
    const float* __restrict__ bias1,
    const ushort_t* __restrict__ dwhid, // [12][512*128]
    const float* __restrict__ dwin,     // [12][1024]
    const float* __restrict__ dbin,     // [12][512]
    const float* __restrict__ dbhid,    // [12][512]
    const float* __restrict__ dwout,    // [12][4*128]
    const float* __restrict__ dbout,    // [12][4]
    const unsigned* __restrict__ maskw, // [1048576]
    float* __restrict__ out){
  __shared__ __align__(16) ushort_t H0s[BT * PITCH];
  __shared__ __align__(16) ushort_t HDs[BT * PITCH];
  __shared__ __align__(16) ushort_t H1s[BT * PITCH];
  __shared__ float OBSs[BT * 16];
  __shared__ float XDs[BT * 2];

  const int tid = threadIdx.x;
  const int wv = tid >> 6;      // wave 0..7
  const int l  = tid & 63;
  const int lx = l & 15;        // A-row / B-col / D-col selector
  const int lg = l >> 4;        // k-group / D-row-group
  const int b0 = blockIdx.x * BT;
  const int hj = 16 * wv + lx;  // hidden col owned by this lane

  for (int i = tid; i < BT * 16; i += 512) OBSs[i] = obs[b0 * 16 + i];
  for (int i = tid; i < BT * PITCH; i += 512){ H0s[i] = 0; H1s[i] = 0; }

  float c0v[16], c1v[16];
  #pragma unroll
  for (int i = 0; i < 16; ++i){ c0v[i] = 0.f; c1v[i] = 0.f; }

  float b0g[4], b1g[4], wx0g[4], wx1g[4];
  #pragma unroll
  for (int g = 0; g < 4; ++g){
    int j = 128 * g + hj;
    b0g[g] = bias0[j]; b1g[g] = bias1[j];
    wx0g[g] = wih0[2 * j]; wx1g[g] = wih0[2 * j + 1];
  }
  __syncthreads();

  f32x4 acc[4][4];
  const f32x4 zero4 = {0.f, 0.f, 0.f, 0.f};

  // ================= encoder: 8 steps, two stacked layers =================
  for (int t = 0; t < 8; ++t){
    // ---- layer 0 ----
    #pragma unroll
    for (int g = 0; g < 4; ++g)
      #pragma unroll
      for (int mt = 0; mt < 4; ++mt) acc[g][mt] = zero4;
    gemm_k128(H0s, whh0, wv, lx, lg, acc);
    __syncthreads();
    #pragma unroll
    for (int mt = 0; mt < 4; ++mt){
      #pragma unroll
      for (int e = 0; e < 4; ++e){
        int r = 16 * mt + 4 * lg + e;
        float x0 = OBSs[r * 16 + 2 * t], x1 = OBSs[r * 16 + 2 * t + 1];
        float gi = acc[0][mt][e] + b0g[0] + x0 * wx0g[0] + x1 * wx1g[0];
        float gf = acc[1][mt][e] + b0g[1] + x0 * wx0g[1] + x1 * wx1g[1];
        float gg = acc[2][mt][e] + b0g[2] + x0 * wx0g[2] + x1 * wx1g[2];
        float go = acc[3][mt][e] + b0g[3] + x0 * wx0g[3] + x1 * wx1g[3];
        float cn = sigmf(gf) * c0v[4 * mt + e] + sigmf(gi) * tanhf_(gg);
        c0v[4 * mt + e] = cn;
        float hn = sigmf(go) * tanhf_(cn);
        H0s[r * PITCH + hj] = f2bf(hn);
        unsigned idx = ((unsigned)(b0 + r) << 10) | ((unsigned)t << 7) | (unsigned)hj;
        unsigned keep = (maskw[idx >> 5] >> (idx & 31u)) & 1u;
        HDs[r * PITCH + hj] = f2bf(keep ? hn * (1.0f / 0.9f) : 0.0f);
      }
    }
    __syncthreads();
    // ---- layer 1 (K=256: dropped h0, then own h1) ----
    #pragma unroll
    for (int g = 0; g < 4; ++g)
      #pragma unroll
      for (int mt = 0; mt < 4; ++mt) acc[g][mt] = zero4;
    gemm_k128(HDs, wih1, wv, lx, lg, acc);
    gemm_k128(H1s, whh1, wv, lx, lg, acc);
    __syncthreads();
    #pragma unroll
    for (int mt = 0; mt < 4; ++mt){
      #pragma unroll
      for (int e = 0; e < 4; ++e){
        int r = 16 * mt + 4 * lg + e;
        float gi = acc[0][mt][e] + b1g[0];
        float gf = acc[1][mt][e] + b1g[1];
        float gg = acc[2][mt][e] + b1g[2];
        float go = acc[3][mt][e] + b1g[3];
        float cn = sigmf(gf) * c1v[4 * mt + e] + sigmf(gi) * tanhf_(gg);
        c1v[4 * mt + e] = cn;
        float hn = sigmf(go) * tanhf_(cn);
        H1s[r * PITCH + hj] = f2bf(hn);
      }
    }
    __syncthreads();
  }

  // decoder initial x = obs[:, 7, :]
  if (tid < 128) XDs[tid] = OBSs[(tid >> 1) * 16 + 14 + (tid & 1)];
  __syncthreads();

  // ================= decoder: 12 steps =================
  for (int s = 0; s < 12; ++s){
    #pragma unroll
    for (int g = 0; g < 4; ++g)
      #pragma unroll
      for (int mt = 0; mt < 4; ++mt) acc[g][mt] = zero4;
    gemm_k128(H1s, dwhid + s * 65536, wv, lx, lg, acc);
    __syncthreads();
    const float* bin  = dbin  + s * 512;
    const float* bhid = dbhid + s * 512;
    const float* win  = dwin  + s * 1024;
    float bg[4], wa[4], wb[4];
    #pragma unroll
    for (int g = 0; g < 4; ++g){
      int j = 128 * g + hj;
      bg[g] = bin[j] + bhid[j];
      wa[g] = win[2 * j]; wb[g] = win[2 * j + 1];
    }
    #pragma unroll
    for (int mt = 0; mt < 4; ++mt){
      #pragma unroll
      for (int e = 0; e < 4; ++e){
        int r = 16 * mt + 4 * lg + e;
        float x0 = XDs[2 * r], x1 = XDs[2 * r + 1];
        float gi = acc[0][mt][e] + bg[0] + x0 * wa[0] + x1 * wb[0];
        float gf = acc[1][mt][e] + bg[1] + x0 * wa[1] + x1 * wb[1];
        float gg = acc[2][mt][e] + bg[2] + x0 * wa[2] + x1 * wb[2];
        float go = acc[3][mt][e] + bg[3] + x0 * wa[3] + x1 * wb[3];
        float cn = sigmf(gf) * c1v[4 * mt + e] + sigmf(gi) * tanhf_(gg);
        c1v[4 * mt + e] = cn;
        float hn = sigmf(go) * tanhf_(cn);
        H1s[r * PITCH + hj] = f2bf(hn);
      }
    }
    __syncthreads();
    // out head: out = h_new @ w_out^T + b_out (4 cols); mu feedback + clip(log_sigma)
    if (tid < 256){
      int r = tid >> 2, o = tid & 3;
      const float* wo = dwout + s * 512 + o * 128;
      float sum = dbout[s * 4 + o];
      #pragma unroll 8
      for (int k = 0; k < 128; ++k) sum += bf2f(H1s[r * PITCH + k]) * wo[k];
      int gb = b0 + r;
      if (o < 2){
        out[gb * 24 + s * 2 + o] = sum;
        XDs[2 * r + o] = sum;       // unclipped mu feedback
      } else {
        float ls = fminf(fmaxf(sum, -4.0f), 2.0f);
        out[786432 + gb * 24 + s * 2 + (o - 2)] = ls;
      }
    }
    __syncthreads();
  }
}

// ---------------- launch ----------------
extern "C" void kernel_launch(void* const* d_in, const int* in_sizes, int n_in,
                              void* d_out, int out_size, void* d_ws, size_t ws_size,
                              hipStream_t stream){
  (void)in_sizes; (void)n_in; (void)out_size; (void)ws_size;
  const float* obs   = (const float*)d_in[0];
  const float* wih0  = (const float*)d_in[1];
  const float* whh0f = (const float*)d_in[2];
  const float* bih0  = (const float*)d_in[3];
  const float* bhh0  = (const float*)d_in[4];
  const float* wih1f = (const float*)d_in[5];
  const float* whh1f = (const float*)d_in[6];
  const float* bih1  = (const float*)d_in[7];
  const float* bhh1  = (const float*)d_in[8];
  const float* din_wmu  = (const float*)d_in[9];
  const float* din_wrho = (const float*)d_in[10];
  const float* din_bmu  = (const float*)d_in[11];
  const float* din_brho = (const float*)d_in[12];
  const float* dhid_wmu  = (const float*)d_in[13];
  const float* dhid_wrho = (const float*)d_in[14];
  const float* dhid_bmu  = (const float*)d_in[15];
  const float* dhid_brho = (const float*)d_in[16];
  const float* out_wmu  = (const float*)d_in[17];
  const float* out_wrho = (const float*)d_in[18];
  const float* out_bmu  = (const float*)d_in[19];
  const float* out_brho = (const float*)d_in[20];

  char* wsb = (char*)d_ws;
  ushort_t* whh0b = (ushort_t*)(wsb + 0);        // 512*128 bf16
  ushort_t* wih1b = (ushort_t*)(wsb + 131072);
  ushort_t* whh1b = (ushort_t*)(wsb + 262144);
  float* bias0    = (float*)(wsb + 393216);      // 512 f32
  float* bias1    = (float*)(wsb + 395264);
  ushort_t* dwhid = (ushort_t*)(wsb + 397312);   // 12 * 512*128 bf16
  float* dwin     = (float*)(wsb + 1970176);     // 12 * 1024
  float* dbin     = (float*)(wsb + 2019328);     // 12 * 512
  float* dbhid    = (float*)(wsb + 2043904);     // 12 * 512
  float* dwout    = (float*)(wsb + 2068480);     // 12 * 512
  float* dbout    = (float*)(wsb + 2093056);     // 12 * 4
  unsigned* maskw = (unsigned*)(wsb + 2093248);  // 1048576 words (33.5M bits)

  prep_enc<<<772, 256, 0, stream>>>(whh0f, wih1f, whh1f, bih0, bhh0, bih1, bhh1,
                                    whh0b, wih1b, whh1b, bias0, bias1);
  prep_dec<<<(12 * 68100 + 255) / 256, 256, 0, stream>>>(
      din_wmu, din_wrho, din_bmu, din_brho,
      dhid_wmu, dhid_wrho, dhid_bmu, dhid_brho,
      out_wmu, out_wrho, out_bmu, out_brho,
      dwhid, dwin, dbin, dbhid, dwout, dbout);
  gen_mask<<<4096, 256, 0, stream>>>(maskw);
  kl_kernel<<<1, 1024, 0, stream>>>(din_wmu, din_wrho, din_bmu, din_brho,
                                    dhid_wmu, dhid_wrho, dhid_bmu, dhid_brho,
                                    out_wmu, out_wrho, out_bmu, out_brho,
                                    (float*)d_out);
  lstm_main<<<512, 512, 0, stream>>>(obs, wih0, whh0b, wih1b, whh1b, bias0, bias1,
                                     dwhid, dwin, dbin, dbhid, dwout, dbout, maskw,
                                     (float*)d_out);
}